// Round 7
// baseline (120.309 us; speedup 1.0000x reference)
//
#include <hip/hip_runtime.h>
#include <stdint.h>
#include <stddef.h>

// AdderNet 2D: out[n,f,i,j] = -sum_{c,kh,kw} |xpad[n,c,i+kh,j+kw] - W[f,c,kh,kw]|
// x: [16,32,56,56] f32, W: [64,32,3,3] f32, out: [16,64,56,56] f32. PAD=1, STRIDE=1.
//
// R7: w broadcast through the VMEM/L1 path (wave-uniform buffer_load_dwordx4 = one
// cache-line request) -- SMEM (R5: SQC miss drains) and LDS (R6: 80us of LDS-pipe
// wall, 4 SIMDs share 1 pipe) are both proven dead ends for broadcasts here.
// Wave = 2 output rows x 56 cols (lane=col) x 8 filters. x via per-row buffer SRDs
// (HW OOB-zero == zero-pad semantics). 3584 one-wave blocks = 14 waves/CU balanced.

#define N_   16
#define C_   32
#define H_   56
#define F_   64
#define HW_  3136
#define FPW  8
#define NFG  8
#define ROWB 224                      // bytes per x row
#define WQ_ELTS (C_ * NFG * 96)      // 24576 floats = 96 KB in ws
#define ROWS 2

typedef int   int32x4 __attribute__((ext_vector_type(4)));
typedef float f32x4   __attribute__((ext_vector_type(4)));

__device__ float __buf_load_f32(int32x4 srsrc, int voffset, int soffset, int aux) __asm("llvm.amdgcn.raw.buffer.load.f32");
__device__ f32x4 __buf_load_v4 (int32x4 srsrc, int voffset, int soffset, int aux) __asm("llvm.amdgcn.raw.buffer.load.v4f32");

__device__ inline int32x4 make_srd(const void* p, int bytes) {
    union { const void* p; uint32_t u[2]; } a; a.p = p;
    int32x4 r;
    r.x = (int)a.u[0];
    r.y = (int)a.u[1];        // VA < 2^48, high bits 0 -> stride field 0
    r.z = bytes;              // num_records (stride==0 -> bytes)
    r.w = 0x00020000;         // raw untyped dword
    return r;
}

// wq[(c*NFG+fg)*96 + fi*9 + kk] = W[(fg*8+fi)*288 + c*9 + kk], pad [72..95]=0
__global__ __launch_bounds__(64)
void prep_w(const float* __restrict__ w, float* __restrict__ wq) {
    int idx = blockIdx.x * 64 + threadIdx.x;
    if (idx >= WQ_ELTS) return;
    int slot = idx % 96;
    int cg   = idx / 96;          // c*NFG + fg
    int c    = cg / NFG;
    int fg   = cg % NFG;
    int fi   = slot / 9;
    int kk   = slot % 9;
    float v = 0.0f;
    if (slot < 72)
        v = w[((fg * 8 + fi) * C_ + c) * 9 + kk];
    wq[idx] = v;
}

__global__ __launch_bounds__(64, 4)   // cap VGPR so 16 waves/CU fit (need 14)
void adder_main(const float* __restrict__ x,
                const float* __restrict__ wq,
                float* __restrict__ out) {
    const int lane = threadIdx.x & 63;
    const int bid  = blockIdx.x;
    const int fg   = bid & (NFG - 1);
    const int bid2 = bid >> 3;
    const int rp   = bid2 % (H_ / ROWS);   // row pair 0..27
    const int n    = bid2 / (H_ / ROWS);
    const int row  = rp * ROWS;            // first output row (0..54)
    const int f0   = fg * FPW;

    const int vA = (lane - 1) * 4;   // col j-1 (lane 0 -> 0xFFFFFFFC -> HW OOB zero)
    const int vB = lane * 4;         // col j   (+soffset 4 -> col j+1)

    // x window rows row-1 .. row+2; first/last may be out of image (wave-uniform)
    const int nr0 = (row >= 1)      ? ROWB : 0;
    const int nr3 = (row <= H_ - 3) ? ROWB : 0;

    const float* xb = x + (size_t)n * C_ * HW_ + (ptrdiff_t)(row - 1) * H_;

    const int32x4 wsrd = make_srd(wq, WQ_ELTS * 4);
    const int wbase = fg * 96 * 4;   // byte offset of this fg's slice within a channel

    float acc[FPW][ROWS];
#pragma unroll
    for (int f = 0; f < FPW; ++f)
#pragma unroll
        for (int r = 0; r < ROWS; ++r) acc[f][r] = 0.0f;

    // xw[xr][q]: x at (row-1+xr, col j-1+q), xr=0..3, q=0..2
    float xwa[4][3], xwb[4][3];

    auto load_x = [&](int c, float (*v)[3]) {
        const float* b = xb + (size_t)c * HW_;
        int32x4 s0 = make_srd(b,          nr0);
        int32x4 s1 = make_srd(b + H_,     ROWB);
        int32x4 s2 = make_srd(b + 2 * H_, ROWB);
        int32x4 s3 = make_srd(b + 3 * H_, nr3);
        v[0][0] = __buf_load_f32(s0, vA, 0, 0);
        v[0][1] = __buf_load_f32(s0, vB, 0, 0);
        v[0][2] = __buf_load_f32(s0, vB, 4, 0);
        v[1][0] = __buf_load_f32(s1, vA, 0, 0);
        v[1][1] = __buf_load_f32(s1, vB, 0, 0);
        v[1][2] = __buf_load_f32(s1, vB, 4, 0);
        v[2][0] = __buf_load_f32(s2, vA, 0, 0);
        v[2][1] = __buf_load_f32(s2, vB, 0, 0);
        v[2][2] = __buf_load_f32(s2, vB, 4, 0);
        v[3][0] = __buf_load_f32(s3, vA, 0, 0);
        v[3][1] = __buf_load_f32(s3, vB, 0, 0);
        v[3][2] = __buf_load_f32(s3, vB, 4, 0);
    };

    auto compute = [&](int c, const float (*xw)[3]) {
        const int cb = c * (NFG * 96 * 4) + wbase;
#pragma unroll
        for (int g = 0; g < 2; ++g) {          // filter half-groups: f = g*4 .. g*4+3
            f32x4 wv[9];                        // 36 floats = filters g*4..g*4+3
#pragma unroll
            for (int j = 0; j < 9; ++j)
                wv[j] = __buf_load_v4(wsrd, j * 16, cb + g * 144, 0);  // uniform -> 1 line
#pragma unroll
            for (int fi = 0; fi < 4; ++fi) {
#pragma unroll
                for (int kh = 0; kh < 3; ++kh) {
#pragma unroll
                    for (int kw = 0; kw < 3; ++kw) {
                        const int i = fi * 9 + kh * 3 + kw;
                        const float wf = wv[i >> 2][i & 3];
                        acc[g * 4 + fi][0] += fabsf(xw[kh][kw]     - wf);
                        acc[g * 4 + fi][1] += fabsf(xw[kh + 1][kw] - wf);
                    }
                }
            }
        }
    };

    load_x(0, xwa);
    for (int c = 0; c < C_; c += 2) {
        load_x(c + 1, xwb);
        compute(c, xwa);
        if (c + 2 < C_) load_x(c + 2, xwa);
        compute(c + 1, xwb);
    }

    if (lane < H_) {
#pragma unroll
        for (int f = 0; f < FPW; ++f)
#pragma unroll
            for (int r = 0; r < ROWS; ++r)
                out[(size_t)(n * F_ + f0 + f) * HW_ + (row + r) * H_ + lane] = -acc[f][r];
    }
}

extern "C" void kernel_launch(void* const* d_in, const int* in_sizes, int n_in,
                              void* d_out, int out_size, void* d_ws, size_t ws_size,
                              hipStream_t stream) {
    const float* x = (const float*)d_in[0];
    const float* w = (const float*)d_in[1];
    float* out = (float*)d_out;
    float* wqp = (float*)d_ws;    // 96 KB scratch

    prep_w<<<dim3((WQ_ELTS + 63) / 64), dim3(64), 0, stream>>>(w, wqp);
    adder_main<<<dim3(N_ * (H_ / ROWS) * NFG), dim3(64), 0, stream>>>(x, wqp, out);
}

// Round 8
// 112.704 us; speedup vs baseline: 1.0675x; 1.0675x over previous
//
#include <hip/hip_runtime.h>
#include <stdint.h>
#include <stddef.h>

// AdderNet 2D: out[n,f,i,j] = -sum_{c,kh,kw} |xpad[n,c,i+kh,j+kw] - W[f,c,kh,kw]|
// x: [16,32,56,56] f32, W: [64,32,3,3] f32, out: [16,64,56,56] f32. PAD=1, STRIDE=1.
//
// R8: w-in-LDS with amortization fixed. Wave = 4 rows x 56 cols x 4 filters:
// per channel 9 broadcast ds_read_b128 (36 w floats) feed 288 VALU instrs
// (ratio 0.8 vs R6's 1.33 that saturated the shared LDS pipe). Block = 4 waves
// = 4 filter-quads of one 4-row group; stages 16 filters' w (18.4 KB) once.
// x via per-row buffer SRDs (HW OOB-zero == zero-pad), 2-deep double buffer.
// Measured dead ends: w-SMEM (77us, SQC drains), w-LDS@FPW8ROWS1 (89us, LDS pipe),
// w-VMEM-uniform (120us, unhidden L1 latency).

#define N_   16
#define C_   32
#define H_   56
#define F_   64
#define HW_  3136
#define ROWS 4
#define FPW  4
#define ROWB 224
#define TPB  256

typedef int   int32x4 __attribute__((ext_vector_type(4)));
typedef float f32x4   __attribute__((ext_vector_type(4)));

__device__ float __buf_load_f32(int32x4 srsrc, int voffset, int soffset, int aux) __asm("llvm.amdgcn.raw.buffer.load.f32");

__device__ inline int32x4 make_srd(const void* p, int bytes) {
    union { const void* p; uint32_t u[2]; } a; a.p = p;
    int32x4 r;
    r.x = (int)a.u[0];
    r.y = (int)a.u[1];        // VA < 2^48, high bits 0 -> stride field 0
    r.z = bytes;              // num_records (stride==0 -> bytes)
    r.w = 0x00020000;         // raw untyped dword
    return r;
}

__global__ __launch_bounds__(TPB, 4)   // 4 blocks/CU -> 16 waves/CU, VGPR cap 128
void adder_main(const float* __restrict__ x,
                const float* __restrict__ w,
                float* __restrict__ out) {
    // lds_w[(c*4 + q)*36 + fi*9 + kk] = W[(bq*16 + q*4 + fi)*288 + c*9 + kk]
    __shared__ __align__(16) float lds_w[C_ * 4 * 36];   // 18432 B

    const int tid  = threadIdx.x;
    const int lane = tid & 63;
    const int bid  = blockIdx.x;
    const int bq   = bid & 3;                 // filter 16-block: filters bq*16..bq*16+15
    const int bid2 = bid >> 2;
    const int rg   = bid2 % (H_ / ROWS);      // row group 0..13
    const int n    = bid2 / (H_ / ROWS);
    const int row0 = rg * ROWS;

    // ---- stage 16 filters' weights, transposed to [c][q][fi][kk] ----
    for (int e = tid; e < C_ * 144; e += TPB) {
        const int c  = e / 144;
        const int r  = e % 144;
        const int q_ = r / 36;
        const int s  = r % 36;
        const int fi = s / 9;
        const int kk = s % 9;
        lds_w[e] = w[((bq * 16 + q_ * 4 + fi) * C_ + c) * 9 + kk];
    }
    __syncthreads();

    // wave -> filter quad; force scalar (compiler can't prove wid uniform, R4 lesson)
    const int q  = __builtin_amdgcn_readfirstlane(tid >> 6);   // 0..3
    const int f0 = bq * 16 + q * FPW;

    const int vA = (lane - 1) * 4;   // col j-1 (lane 0 -> 0xFFFFFFFC -> HW OOB zero)
    const int vB = lane * 4;         // col j   (+soffset 4 -> col j+1)

    // 6 x row-slots: slot r <-> image row row0-1+r; validity wave-uniform
    const int nr0 = (row0 >= 1)          ? ROWB : 0;   // slot 0
    const int nr5 = (row0 + 4 <= H_ - 1) ? ROWB : 0;   // slot 5

    const float* xb = x + (size_t)n * C_ * HW_ + (ptrdiff_t)(row0 - 1) * H_;

    float acc[FPW][ROWS];
#pragma unroll
    for (int f = 0; f < FPW; ++f)
#pragma unroll
        for (int r = 0; r < ROWS; ++r) acc[f][r] = 0.0f;

    float xwa[6][3], xwb[6][3];   // [row slot][kw]

    auto load_x = [&](int c, float (*v)[3]) {
        const float* b = xb + (size_t)c * HW_;
#pragma unroll
        for (int s = 0; s < 6; ++s) {
            const int nr = (s == 0) ? nr0 : (s == 5) ? nr5 : ROWB;
            int32x4 srd = make_srd(b + s * H_, nr);
            v[s][0] = __buf_load_f32(srd, vA, 0, 0);
            v[s][1] = __buf_load_f32(srd, vB, 0, 0);
            v[s][2] = __buf_load_f32(srd, vB, 4, 0);
        }
    };

    auto compute = [&](int c, const float (*xw)[3]) {
        const f32x4* wp = (const f32x4*)&lds_w[(c * 4 + q) * 36];
        f32x4 wv[9];
#pragma unroll
        for (int j = 0; j < 9; ++j) wv[j] = wp[j];    // 9 broadcast ds_read_b128
#pragma unroll
        for (int fi = 0; fi < FPW; ++fi) {
#pragma unroll
            for (int kh = 0; kh < 3; ++kh) {
#pragma unroll
                for (int kw = 0; kw < 3; ++kw) {
                    const int i = fi * 9 + kh * 3 + kw;
                    const float wf = wv[i >> 2][i & 3];
#pragma unroll
                    for (int r = 0; r < ROWS; ++r)
                        acc[fi][r] += fabsf(xw[r + kh][kw] - wf);
                }
            }
        }
    };

    load_x(0, xwa);
    for (int c = 0; c < C_; c += 2) {
        load_x(c + 1, xwb);
        compute(c, xwa);
        if (c + 2 < C_) load_x(c + 2, xwa);
        compute(c + 1, xwb);
    }

    if (lane < H_) {
#pragma unroll
        for (int fi = 0; fi < FPW; ++fi)
#pragma unroll
            for (int r = 0; r < ROWS; ++r)
                out[(size_t)(n * F_ + f0 + fi) * HW_ + (row0 + r) * H_ + lane] = -acc[fi][r];
    }
}

extern "C" void kernel_launch(void* const* d_in, const int* in_sizes, int n_in,
                              void* d_out, int out_size, void* d_ws, size_t ws_size,
                              hipStream_t stream) {
    const float* x = (const float*)d_in[0];
    const float* w = (const float*)d_in[1];
    float* out = (float*)d_out;
    adder_main<<<dim3(N_ * (H_ / ROWS) * 4), dim3(TPB), 0, stream>>>(x, w, out);
}

// Round 9
// 85.939 us; speedup vs baseline: 1.3999x; 1.3114x over previous
//
#include <hip/hip_runtime.h>
#include <stdint.h>
#include <stddef.h>

// AdderNet 2D: out[n,f,i,j] = -sum_{c,kh,kw} |xpad[n,c,i+kh,j+kw] - W[f,c,kh,kw]|
// x: [16,32,56,56] f32, W: [64,32,3,3] f32, out: [16,64,56,56] f32. PAD=1, STRIDE=1.
//
// R9 = R8 geometry (wave = 4 rows x 56 cols x 4 filters; w in LDS, 9 broadcast
// ds_read_b128/ch; x via per-row buffer SRDs with HW OOB-zero == zero-pad) with
// codegen fixed: macros instead of lambdas (SROA keeps x tiles in VGPRs),
// sched_barrier(0) fences pinning the 2-deep x prefetch (stop load sinking),
// and #pragma unroll 1 on the c-loop (keep body I-cache resident).
// Measured dead ends: w-SMEM 77us (SQC serialization), w-LDS@FPW8 89us (LDS pipe),
// w-VMEM-uniform 120us (unhidden latency), R8 113us (compiler sank prefetch).

#define N_   16
#define C_   32
#define H_   56
#define F_   64
#define HW_  3136
#define ROWS 4
#define FPW  4
#define ROWB 224
#define TPB  256

typedef int   int32x4 __attribute__((ext_vector_type(4)));
typedef float f32x4   __attribute__((ext_vector_type(4)));

__device__ float __buf_load_f32(int32x4 srsrc, int voffset, int soffset, int aux) __asm("llvm.amdgcn.raw.buffer.load.f32");

__device__ inline int32x4 make_srd(const void* p, int bytes) {
    union { const void* p; uint32_t u[2]; } a; a.p = p;
    int32x4 r;
    r.x = (int)a.u[0];
    r.y = (int)a.u[1];        // VA < 2^48, high bits 0 -> stride field 0
    r.z = bytes;              // num_records (stride==0 -> bytes)
    r.w = 0x00020000;         // raw untyped dword
    return r;
}

// issue 18 buffer loads for channel (c) into named array V (6 row slots x 3 taps)
#define LOADX(V, c)                                                         \
    do {                                                                    \
        const float* bp_ = xbase + (size_t)(c) * HW_;                       \
        _Pragma("unroll")                                                   \
        for (int s_ = 0; s_ < 6; ++s_) {                                    \
            const int nr_ = (s_ == 0) ? nr0 : (s_ == 5) ? nr5 : ROWB;       \
            int32x4 srd_ = make_srd(bp_ + s_ * H_, nr_);                    \
            V[s_][0] = __buf_load_f32(srd_, vA, 0, 0);                      \
            V[s_][1] = __buf_load_f32(srd_, vB, 0, 0);                      \
            V[s_][2] = __buf_load_f32(srd_, vB, 4, 0);                      \
        }                                                                   \
    } while (0)

// 9 broadcast ds_read_b128 for channel (c) + 288 VALU into acc
#define COMPUTE(V, c)                                                       \
    do {                                                                    \
        const f32x4* wp_ = (const f32x4*)&lds_w[((c) * 4 + q) * 36];        \
        f32x4 wv_[9];                                                       \
        _Pragma("unroll")                                                   \
        for (int j_ = 0; j_ < 9; ++j_) wv_[j_] = wp_[j_];                   \
        _Pragma("unroll")                                                   \
        for (int fi_ = 0; fi_ < FPW; ++fi_) {                               \
            _Pragma("unroll")                                               \
            for (int kh_ = 0; kh_ < 3; ++kh_) {                             \
                _Pragma("unroll")                                           \
                for (int kw_ = 0; kw_ < 3; ++kw_) {                         \
                    const int i_ = fi_ * 9 + kh_ * 3 + kw_;                 \
                    const float wf_ = wv_[i_ >> 2][i_ & 3];                 \
                    _Pragma("unroll")                                       \
                    for (int r_ = 0; r_ < ROWS; ++r_)                       \
                        acc[fi_][r_] += fabsf(V[r_ + kh_][kw_] - wf_);      \
                }                                                           \
            }                                                               \
        }                                                                   \
    } while (0)

__global__ __launch_bounds__(TPB, 4)   // 4 blocks/CU -> 16 waves/CU, VGPR cap 128
void adder_main(const float* __restrict__ x,
                const float* __restrict__ w,
                float* __restrict__ out) {
    // lds_w[(c*4 + q)*36 + fi*9 + kk] = W[(bq*16 + q*4 + fi)*288 + c*9 + kk]
    __shared__ __align__(16) float lds_w[C_ * 4 * 36];   // 18432 B

    const int tid  = threadIdx.x;
    const int lane = tid & 63;
    const int bid  = blockIdx.x;
    const int bq   = bid & 3;                 // filters bq*16 .. bq*16+15
    const int bid2 = bid >> 2;
    const int rg   = bid2 % (H_ / ROWS);      // row group 0..13
    const int n    = bid2 / (H_ / ROWS);
    const int row0 = rg * ROWS;

    // ---- stage 16 filters' weights, transposed to [c][q][fi][kk] ----
    for (int e = tid; e < C_ * 144; e += TPB) {
        const int c  = e / 144;
        const int r  = e % 144;
        const int q_ = r / 36;
        const int s  = r % 36;
        const int fi = s / 9;
        const int kk = s % 9;
        lds_w[e] = w[((bq * 16 + q_ * 4 + fi) * C_ + c) * 9 + kk];
    }
    __syncthreads();

    // wave -> filter quad; force scalar (compiler can't prove wid uniform, R4 lesson)
    const int q  = __builtin_amdgcn_readfirstlane(tid >> 6);   // 0..3
    const int f0 = bq * 16 + q * FPW;

    const int vA = (lane - 1) * 4;   // col j-1 (lane 0 -> 0xFFFFFFFC -> HW OOB zero)
    const int vB = lane * 4;         // col j   (+soffset 4 -> col j+1)

    // 6 x row-slots: slot s <-> image row row0-1+s; validity wave-uniform
    const int nr0 = (row0 >= 1)          ? ROWB : 0;   // slot 0
    const int nr5 = (row0 + 4 <= H_ - 1) ? ROWB : 0;   // slot 5

    const float* xbase = x + (size_t)n * C_ * HW_ + (ptrdiff_t)(row0 - 1) * H_;

    float acc[FPW][ROWS];
#pragma unroll
    for (int f = 0; f < FPW; ++f)
#pragma unroll
        for (int r = 0; r < ROWS; ++r) acc[f][r] = 0.0f;

    float xa[6][3], xb[6][3];   // [row slot][kw tap], explicit double buffer

    LOADX(xa, 0);
#pragma unroll 1
    for (int c = 0; c < C_; c += 2) {
        LOADX(xb, c + 1);                       // issue next-channel loads first
        __builtin_amdgcn_sched_barrier(0);
        COMPUTE(xa, c);
        __builtin_amdgcn_sched_barrier(0);
        if (c + 2 < C_) LOADX(xa, c + 2);
        __builtin_amdgcn_sched_barrier(0);
        COMPUTE(xb, c + 1);
        __builtin_amdgcn_sched_barrier(0);
    }

    if (lane < H_) {
#pragma unroll
        for (int fi = 0; fi < FPW; ++fi)
#pragma unroll
            for (int r = 0; r < ROWS; ++r)
                out[(size_t)(n * F_ + f0 + fi) * HW_ + (row0 + r) * H_ + lane] = -acc[fi][r];
    }
}

extern "C" void kernel_launch(void* const* d_in, const int* in_sizes, int n_in,
                              void* d_out, int out_size, void* d_ws, size_t ws_size,
                              hipStream_t stream) {
    const float* x = (const float*)d_in[0];
    const float* w = (const float*)d_in[1];
    float* out = (float*)d_out;
    adder_main<<<dim3(N_ * (H_ / ROWS) * 4), dim3(TPB), 0, stream>>>(x, w, out);
}

// Round 10
// 79.162 us; speedup vs baseline: 1.5198x; 1.0856x over previous
//
#include <hip/hip_runtime.h>
#include <stdint.h>
#include <stddef.h>

// AdderNet 2D: out[n,f,i,j] = -sum_{c,kh,kw} |xpad[n,c,i+kh,j+kw] - W[f,c,kh,kw]|
// x: [16,32,56,56] f32, W: [64,32,3,3] f32, out: [16,64,56,56] f32. PAD=1, STRIDE=1.
//
// R10: occupancy attack. Wave = 4 rows x 56 cols x 2 filters (was x4) -> 7168 waves
// = 28/CU = 7/SIMD (R3-R9 never exceeded 3.5/SIMD; ~66us of R9's 93 was stall).
// Single x buffer (TLP hides latency at 7 waves/SIMD; dbuf never fit in VGPRs anyway).
// w in LDS, per channel 4x ds_read_b128 + 1x b64 broadcast (pipe ratio 0.78 < 1).
// x via per-row buffer SRDs: HW OOB-zero == reference zero-pad semantics.
// Measured dead ends: w-SMEM 77us (SQC drains), w-LDS@ratio1.33 89us (LDS pipe),
// w-VMEM-uniform 120us (unhidden latency), sunk-prefetch 113us, 3.5 waves/SIMD 86us.

#define N_   16
#define C_   32
#define H_   56
#define F_   64
#define HW_  3136
#define ROWS 4
#define ROWB 224
#define TPB  256
#define WSTR 20          // floats per filter-pair slot (18 used; 80B stride keeps 16B align)

typedef int   int32x4 __attribute__((ext_vector_type(4)));
typedef float f32x4   __attribute__((ext_vector_type(4)));
typedef float f32x2   __attribute__((ext_vector_type(2)));

__device__ float __buf_load_f32(int32x4 srsrc, int voffset, int soffset, int aux) __asm("llvm.amdgcn.raw.buffer.load.f32");

__device__ inline int32x4 make_srd(const void* p, int bytes) {
    union { const void* p; uint32_t u[2]; } a; a.p = p;
    int32x4 r;
    r.x = (int)a.u[0];
    r.y = (int)a.u[1];        // VA < 2^48, high bits 0 -> stride field 0
    r.z = bytes;              // num_records (stride==0 -> bytes)
    r.w = 0x00020000;         // raw untyped dword
    return r;
}

__global__ __launch_bounds__(TPB, 7)   // 7 waves/EU -> VGPR cap 72, 28 waves/CU
void adder_main(const float* __restrict__ x,
                const float* __restrict__ w,
                float* __restrict__ out) {
    // lds_w[(c*8+q)*20 + p*9 + kk] = W[(fo*8 + q*2 + p)*288 + c*9 + kk]
    __shared__ __align__(16) float lds_w[C_ * 8 * WSTR];   // 20480 B

    const int tid  = threadIdx.x;
    const int lane = tid & 63;
    const int bid  = blockIdx.x;
    const int fo   = bid & 7;                 // filter octet: filters fo*8 .. fo*8+7
    const int bid2 = bid >> 3;
    const int rg   = bid2 % (H_ / ROWS);      // row group 0..13
    const int n    = bid2 / (H_ / ROWS);
    const int row0 = rg * ROWS;

    // ---- stage 8 filters' weights, transposed to [c][q(pair)][p][kk] ----
    for (int e = tid; e < C_ * 8 * 18; e += TPB) {
        const int c = e / 144;
        const int r = e % 144;
        const int q_ = r / 18;
        const int s  = r % 18;          // p*9 + kk
        const int p_ = s / 9;
        const int kk = s % 9;
        lds_w[(c * 8 + q_) * WSTR + s] = w[((fo * 8 + q_ * 2 + p_) * C_ + c) * 9 + kk];
    }
    __syncthreads();

    const int q = __builtin_amdgcn_readfirstlane(tid >> 6);   // wave's filter pair 0..3

    const int vA = (lane - 1) * 4;   // col j-1 (lane 0 -> 0xFFFFFFFC -> HW OOB zero)
    const int vB = lane * 4;         // col j   (+soffset 4 -> col j+1)

    // 6 x row-slots: slot s <-> image row row0-1+s; validity wave-uniform
    const int nr0 = (row0 >= 1)          ? ROWB : 0;
    const int nr5 = (row0 + 4 <= H_ - 1) ? ROWB : 0;

    const float* xbase = x + (size_t)n * C_ * HW_ + (ptrdiff_t)(row0 - 1) * H_;

    float acc[2][ROWS];
#pragma unroll
    for (int p = 0; p < 2; ++p)
#pragma unroll
        for (int r = 0; r < ROWS; ++r) acc[p][r] = 0.0f;

    float xv[6][3];

#pragma unroll 1
    for (int c = 0; c < C_; ++c) {
        // 18 x loads (6 rows x 3 taps), coalesced, OOB rows/cols return 0
        const float* bp = xbase + (size_t)c * HW_;
#pragma unroll
        for (int s = 0; s < 6; ++s) {
            const int nr = (s == 0) ? nr0 : (s == 5) ? nr5 : ROWB;
            int32x4 srd = make_srd(bp + s * H_, nr);
            xv[s][0] = __buf_load_f32(srd, vA, 0, 0);
            xv[s][1] = __buf_load_f32(srd, vB, 0, 0);
            xv[s][2] = __buf_load_f32(srd, vB, 4, 0);
        }

        // this pair's 18 w floats: 4x b128 + 1x b64 broadcast reads
        const float* wp = &lds_w[(c * 8 + q) * WSTR];
        f32x4 wv0 = *(const f32x4*)(wp);
        f32x4 wv1 = *(const f32x4*)(wp + 4);
        f32x4 wv2 = *(const f32x4*)(wp + 8);
        f32x4 wv3 = *(const f32x4*)(wp + 12);
        f32x2 wv4 = *(const f32x2*)(wp + 16);

#pragma unroll
        for (int p = 0; p < 2; ++p) {
#pragma unroll
            for (int kh = 0; kh < 3; ++kh) {
#pragma unroll
                for (int kw = 0; kw < 3; ++kw) {
                    const int i = p * 9 + kh * 3 + kw;
                    const float wf = (i < 4)  ? wv0[i]
                                   : (i < 8)  ? wv1[i - 4]
                                   : (i < 12) ? wv2[i - 8]
                                   : (i < 16) ? wv3[i - 12]
                                   :            wv4[i - 16];
#pragma unroll
                    for (int r = 0; r < ROWS; ++r)
                        acc[p][r] += fabsf(xv[r + kh][kw] - wf);
                }
            }
        }
    }

    if (lane < H_) {
#pragma unroll
        for (int p = 0; p < 2; ++p)
#pragma unroll
            for (int r = 0; r < ROWS; ++r)
                out[(size_t)(n * F_ + fo * 8 + q * 2 + p) * HW_ + (row0 + r) * H_ + lane] = -acc[p][r];
    }
}

extern "C" void kernel_launch(void* const* d_in, const int* in_sizes, int n_in,
                              void* d_out, int out_size, void* d_ws, size_t ws_size,
                              hipStream_t stream) {
    const float* x = (const float*)d_in[0];
    const float* w = (const float*)d_in[1];
    float* out = (float*)d_out;
    adder_main<<<dim3(N_ * (H_ / ROWS) * 8), dim3(TPB), 0, stream>>>(x, w, out);
}